// Round 1
// baseline (54.542 us; speedup 1.0000x reference)
//
#include <hip/hip_runtime.h>
#include <math.h>

namespace {
constexpr int G_ = 8;
constexpr int NG_ = 256;
constexpr int H_ = 128;
constexpr int HH_ = 64;
constexpr int M_ = 128;
constexpr int NTOT_ = 2048;
constexpr float TWO_PI_F = 6.28318530717958647692f;
constexpr float SCALE_E = 0.08838834764831845f / 256.0f;  // (1/sqrt(H))/Ng

// workspace offsets (floats)
constexpr size_t OFF_QKVG = 0;                                   // 2048*512
constexpr size_t OFF_AQ = OFF_QKVG + (size_t)NTOT_ * 512;        // G*NG*64 each
constexpr size_t OFF_BQ = OFF_AQ + (size_t)G_ * NG_ * HH_;
constexpr size_t OFF_AK = OFF_BQ + (size_t)G_ * NG_ * HH_;
constexpr size_t OFF_BK = OFF_AK + (size_t)G_ * NG_ * HH_;
constexpr size_t OFF_V  = OFF_BK + (size_t)G_ * NG_ * HH_;       // G*NG*128
constexpr size_t OFF_GF = OFF_V + (size_t)G_ * NG_ * H_;         // 2048
constexpr size_t OFF_F  = OFF_GF + NTOT_;                        // 2048*4 (stride 4)
constexpr size_t OFF_C  = OFF_F + (size_t)NTOT_ * 4;             // G*M*NG each
constexpr size_t OFF_S  = OFF_C + (size_t)G_ * M_ * NG_;
constexpr size_t OFF_WC = OFF_S + (size_t)G_ * M_ * NG_;
constexpr size_t OFF_WS = OFF_WC + (size_t)G_ * M_ * NG_;
constexpr size_t OFF_E  = OFF_WS + (size_t)G_ * M_ * NG_;        // G*NG*NG
}  // namespace

__device__ __forceinline__ float sigmoidf_(float x) { return 1.0f / (1.0f + expf(-x)); }
__device__ __forceinline__ float siluf_(float x) { return x / (1.0f + expf(-x)); }

// K1: QKVG[2048][512] = node_feat(2048x128) @ [W_qkv;W_vg]^T  (NT gemm)
__global__ __launch_bounds__(256) void k1_gemm(
    const float* __restrict__ A, const float* __restrict__ Wqkv,
    const float* __restrict__ Wvg, float* __restrict__ out) {
  __shared__ float AsT[64 * 68];
  __shared__ float BsT[64 * 68];
  const int tid = threadIdx.x;
  const int n0 = blockIdx.x * 64;
  const int c0 = blockIdx.y * 64;
  const int i0 = (tid >> 4) << 2;
  const int j0 = (tid & 15) << 2;
  float acc[4][4] = {};
  for (int kc = 0; kc < 2; ++kc) {
    if (kc) __syncthreads();
#pragma unroll
    for (int it = 0; it < 4; ++it) {
      int f4 = tid + it * 256;
      int row = f4 >> 4;
      int k4 = (f4 & 15) << 2;
      float4 a = *(const float4*)(A + (size_t)(n0 + row) * H_ + kc * 64 + k4);
      AsT[(k4 + 0) * 68 + row] = a.x; AsT[(k4 + 1) * 68 + row] = a.y;
      AsT[(k4 + 2) * 68 + row] = a.z; AsT[(k4 + 3) * 68 + row] = a.w;
      int wr = c0 + row;
      const float* Brow = (wr < 384) ? (Wqkv + (size_t)wr * H_)
                                     : (Wvg + (size_t)(wr - 384) * H_);
      float4 b = *(const float4*)(Brow + kc * 64 + k4);
      BsT[(k4 + 0) * 68 + row] = b.x; BsT[(k4 + 1) * 68 + row] = b.y;
      BsT[(k4 + 2) * 68 + row] = b.z; BsT[(k4 + 3) * 68 + row] = b.w;
    }
    __syncthreads();
#pragma unroll 8
    for (int k = 0; k < 64; ++k) {
      float4 av = *(const float4*)(AsT + k * 68 + i0);
      float4 bv = *(const float4*)(BsT + k * 68 + j0);
      float aa[4] = {av.x, av.y, av.z, av.w};
      float bb[4] = {bv.x, bv.y, bv.z, bv.w};
#pragma unroll
      for (int di = 0; di < 4; ++di)
#pragma unroll
        for (int dj = 0; dj < 4; ++dj)
          acc[di][dj] = fmaf(aa[di], bb[dj], acc[di][dj]);
    }
  }
#pragma unroll
  for (int di = 0; di < 4; ++di) {
    float4 o = {acc[di][0], acc[di][1], acc[di][2], acc[di][3]};
    *(float4*)(out + (size_t)(n0 + i0 + di) * 512 + c0 + j0) = o;
  }
}

// K2: activations, deinterleave, v-gate, per-node gates. One wave per node.
__global__ __launch_bounds__(256) void k2_elem(
    const float* __restrict__ scalars, const float* __restrict__ qkvg,
    const float* __restrict__ Whg, const float* __restrict__ bhg,
    const float* __restrict__ Wmg, const float* __restrict__ bmg,
    const float* __restrict__ bvg,
    float* __restrict__ AQ, float* __restrict__ BQ,
    float* __restrict__ AK, float* __restrict__ BK,
    float* __restrict__ V, float* __restrict__ GF,
    float* __restrict__ out_gate) {
  const int wave = threadIdx.x >> 6;
  const int lane = threadIdx.x & 63;
  const int n = blockIdx.x * 4 + wave;
  const float* row = qkvg + (size_t)n * 512;
  const int g = n >> 8, nl = n & 255;
  const size_t hoff = ((size_t)g * NG_ + nl) * HH_ + lane;
  // q (silu), deinterleaved
  float q0 = siluf_(row[2 * lane]);
  float q1 = siluf_(row[2 * lane + 1]);
  AQ[hoff] = q0;
  BQ[hoff] = q1;
  // k (silu), deinterleaved
  float k0 = siluf_(row[128 + 2 * lane]);
  float k1 = siluf_(row[128 + 2 * lane + 1]);
  AK[hoff] = k0;
  BK[hoff] = k1;
  // v gated
  float v0 = row[256 + lane] * sigmoidf_(row[384 + lane] + bvg[lane]);
  float v1 = row[256 + 64 + lane] * sigmoidf_(row[384 + 64 + lane] + bvg[64 + lane]);
  const size_t voff = ((size_t)g * NG_ + nl) * H_;
  V[voff + lane] = v0;
  V[voff + 64 + lane] = v1;
  // gates (two 128-dots, wave reduce)
  const float* srow = scalars + (size_t)n * H_;
  float s0 = srow[lane], s1 = srow[64 + lane];
  float hg = s0 * Whg[lane] + s1 * Whg[64 + lane];
  float mg = s0 * Wmg[lane] + s1 * Wmg[64 + lane];
#pragma unroll
  for (int off = 32; off; off >>= 1) {
    hg += __shfl_down(hg, off, 64);
    mg += __shfl_down(mg, off, 64);
  }
  if (lane == 0) {
    GF[n] = 1.0f + 0.2f * tanhf(hg + bhg[0]);
    out_gate[n] = sigmoidf_(mg + bmg[0]);
  }
}

// K3: fractional coords f = frac((cell^T)^{-1} p)
__global__ __launch_bounds__(256) void k3_frac(
    const float* __restrict__ cell, const float* __restrict__ pos,
    float* __restrict__ F4) {
  const int g = blockIdx.x;
  const int nl = threadIdx.x;
  const float* cg = cell + (size_t)g * 9;
  // A = cell^T : A[i][j] = cg[j*3+i]
  float A00 = cg[0], A01 = cg[3], A02 = cg[6];
  float A10 = cg[1], A11 = cg[4], A12 = cg[7];
  float A20 = cg[2], A21 = cg[5], A22 = cg[8];
  float b00 = A11 * A22 - A12 * A21;
  float b01 = A02 * A21 - A01 * A22;
  float b02 = A01 * A12 - A02 * A11;
  float b10 = A12 * A20 - A10 * A22;
  float b11 = A00 * A22 - A02 * A20;
  float b12 = A02 * A10 - A00 * A12;
  float b20 = A10 * A21 - A11 * A20;
  float b21 = A01 * A20 - A00 * A21;
  float b22 = A00 * A11 - A01 * A10;
  float det = A00 * b00 + A01 * b10 + A02 * b20;
  float inv = 1.0f / det;
  const int node = g * NG_ + nl;
  float p0 = pos[(size_t)node * 3 + 0];
  float p1 = pos[(size_t)node * 3 + 1];
  float p2 = pos[(size_t)node * 3 + 2];
  float f0 = (b00 * p0 + b01 * p1 + b02 * p2) * inv;
  float f1 = (b10 * p0 + b11 * p1 + b12 * p2) * inv;
  float f2 = (b20 * p0 + b21 * p1 + b22 * p2) * inv;
  f0 -= floorf(f0); f1 -= floorf(f1); f2 -= floorf(f2);
  F4[(size_t)node * 4 + 0] = f0;
  F4[(size_t)node * 4 + 1] = f1;
  F4[(size_t)node * 4 + 2] = f2;
  F4[(size_t)node * 4 + 3] = 0.0f;
}

// K4: trig tables C,S (M x N per group) and weighted copies
__global__ __launch_bounds__(256) void k4_trig(
    const float* __restrict__ F4, const int* __restrict__ nvec,
    const float* __restrict__ w, float* __restrict__ C, float* __restrict__ S,
    float* __restrict__ WC, float* __restrict__ WS) {
  const int idx = blockIdx.x * 256 + threadIdx.x;  // < G*M*NG = 262144
  const int g = idx >> 15;
  const int r = idx & 32767;
  const int m = r >> 8;
  const int n = r & 255;
  const int* nv = nvec + ((size_t)g * M_ + m) * 3;
  const float* f = F4 + ((size_t)g * NG_ + n) * 4;
  float t = f[0] * (float)nv[0] + f[1] * (float)nv[1] + f[2] * (float)nv[2];
  t -= floorf(t);
  float sn, cs;
  sincosf(TWO_PI_F * t, &sn, &cs);
  float wm = w[g * M_ + m];
  const size_t o = ((size_t)g * M_ + m) * NG_ + n;
  C[o] = cs;
  S[o] = sn;
  WC[o] = wm * cs;
  WS[o] = wm * sn;
}

// K5: E[g][n][n'] = Gcos.*Ccos + Gsin.*Csin, tiles 32(rows) x 64(cols)
__global__ __launch_bounds__(256) void k5_E(
    const float* __restrict__ AQ, const float* __restrict__ BQ,
    const float* __restrict__ AK, const float* __restrict__ BK,
    const float* __restrict__ C, const float* __restrict__ S,
    const float* __restrict__ WC, const float* __restrict__ WS,
    float* __restrict__ E) {
  __shared__ float I1[64 * 36];
  __shared__ float I2[64 * 36];
  __shared__ float J1[64 * 68];
  __shared__ float J2[64 * 68];
  const int tid = threadIdx.x;
  const int R0 = blockIdx.x * 32;
  const int C0 = blockIdx.y * 64;
  const int g = blockIdx.z;
  const int i0 = (tid >> 4) << 1;  // 2 rows per thread
  const int j0 = (tid & 15) << 2;  // 4 cols per thread

  // ---- phase A: Gram matrices over channel dim (K=64), transposed staging
#pragma unroll
  for (int it = 0; it < 2; ++it) {
    int f4 = tid + it * 256;
    int rr = f4 >> 4;
    int c4 = (f4 & 15) << 2;
    size_t base = ((size_t)g * NG_ + R0 + rr) * HH_ + c4;
    float4 a = *(const float4*)(AQ + base);
    I1[(c4 + 0) * 36 + rr] = a.x; I1[(c4 + 1) * 36 + rr] = a.y;
    I1[(c4 + 2) * 36 + rr] = a.z; I1[(c4 + 3) * 36 + rr] = a.w;
    float4 b = *(const float4*)(BQ + base);
    I2[(c4 + 0) * 36 + rr] = b.x; I2[(c4 + 1) * 36 + rr] = b.y;
    I2[(c4 + 2) * 36 + rr] = b.z; I2[(c4 + 3) * 36 + rr] = b.w;
  }
#pragma unroll
  for (int it = 0; it < 4; ++it) {
    int f4 = tid + it * 256;
    int jj = f4 >> 4;
    int c4 = (f4 & 15) << 2;
    size_t base = ((size_t)g * NG_ + C0 + jj) * HH_ + c4;
    float4 a = *(const float4*)(AK + base);
    J1[(c4 + 0) * 68 + jj] = a.x; J1[(c4 + 1) * 68 + jj] = a.y;
    J1[(c4 + 2) * 68 + jj] = a.z; J1[(c4 + 3) * 68 + jj] = a.w;
    float4 b = *(const float4*)(BK + base);
    J2[(c4 + 0) * 68 + jj] = b.x; J2[(c4 + 1) * 68 + jj] = b.y;
    J2[(c4 + 2) * 68 + jj] = b.z; J2[(c4 + 3) * 68 + jj] = b.w;
  }
  __syncthreads();
  float gc[2][4] = {}, gs[2][4] = {};
#pragma unroll 8
  for (int k = 0; k < 64; ++k) {
    float aq[2], bq[2];
    aq[0] = I1[k * 36 + i0]; aq[1] = I1[k * 36 + i0 + 1];
    bq[0] = I2[k * 36 + i0]; bq[1] = I2[k * 36 + i0 + 1];
    float4 akv = *(const float4*)(J1 + k * 68 + j0);
    float4 bkv = *(const float4*)(J2 + k * 68 + j0);
    float ak[4] = {akv.x, akv.y, akv.z, akv.w};
    float bk[4] = {bkv.x, bkv.y, bkv.z, bkv.w};
#pragma unroll
    for (int di = 0; di < 2; ++di)
#pragma unroll
      for (int dj = 0; dj < 4; ++dj) {
        gc[di][dj] = fmaf(aq[di], ak[dj], gc[di][dj]);
        gc[di][dj] = fmaf(bq[di], bk[dj], gc[di][dj]);
        gs[di][dj] = fmaf(aq[di], bk[dj], gs[di][dj]);
        gs[di][dj] = fmaf(-bq[di], ak[dj], gs[di][dj]);
      }
  }

  // ---- phase B: Ccos/Csin over m (K=128, 2 chunks of 64), natural staging
  float cc[2][4] = {}, cs[2][4] = {};
  for (int chunk = 0; chunk < 2; ++chunk) {
    __syncthreads();
    const int m0 = chunk * 64;
#pragma unroll
    for (int it = 0; it < 2; ++it) {
      int f4 = tid + it * 256;
      int mm = f4 >> 3;            // 8 float4 per 32-wide row
      int i4 = (f4 & 7) << 2;
      size_t base = ((size_t)g * M_ + m0 + mm) * NG_ + R0 + i4;
      *(float4*)(I1 + mm * 36 + i4) = *(const float4*)(WC + base);
      *(float4*)(I2 + mm * 36 + i4) = *(const float4*)(WS + base);
    }
#pragma unroll
    for (int it = 0; it < 4; ++it) {
      int f4 = tid + it * 256;
      int mm = f4 >> 4;            // 16 float4 per 64-wide row
      int j4 = (f4 & 15) << 2;
      size_t base = ((size_t)g * M_ + m0 + mm) * NG_ + C0 + j4;
      *(float4*)(J1 + mm * 68 + j4) = *(const float4*)(C + base);
      *(float4*)(J2 + mm * 68 + j4) = *(const float4*)(S + base);
    }
    __syncthreads();
#pragma unroll 8
    for (int mm = 0; mm < 64; ++mm) {
      float wc[2], ws[2];
      wc[0] = I1[mm * 36 + i0]; wc[1] = I1[mm * 36 + i0 + 1];
      ws[0] = I2[mm * 36 + i0]; ws[1] = I2[mm * 36 + i0 + 1];
      float4 cv = *(const float4*)(J1 + mm * 68 + j0);
      float4 sv = *(const float4*)(J2 + mm * 68 + j0);
      float cm[4] = {cv.x, cv.y, cv.z, cv.w};
      float sm[4] = {sv.x, sv.y, sv.z, sv.w};
#pragma unroll
      for (int di = 0; di < 2; ++di)
#pragma unroll
        for (int dj = 0; dj < 4; ++dj) {
          cc[di][dj] = fmaf(wc[di], cm[dj], cc[di][dj]);
          cc[di][dj] = fmaf(ws[di], sm[dj], cc[di][dj]);
          cs[di][dj] = fmaf(ws[di], cm[dj], cs[di][dj]);
          cs[di][dj] = fmaf(-wc[di], sm[dj], cs[di][dj]);
        }
    }
  }
  // combine + write
#pragma unroll
  for (int di = 0; di < 2; ++di) {
    float4 o;
    o.x = gc[di][0] * cc[di][0] + gs[di][0] * cs[di][0];
    o.y = gc[di][1] * cc[di][1] + gs[di][1] * cs[di][1];
    o.z = gc[di][2] * cc[di][2] + gs[di][2] * cs[di][2];
    o.w = gc[di][3] * cc[di][3] + gs[di][3] * cs[di][3];
    *(float4*)(E + ((size_t)g * NG_ + R0 + i0 + di) * NG_ + C0 + j0) = o;
  }
}

// K6: update = gate * scale * (E @ V), tiles 32(n) x 64(d), K=256 in 4 chunks
__global__ __launch_bounds__(256) void k6_out(
    const float* __restrict__ E, const float* __restrict__ V,
    const float* __restrict__ GF, float* __restrict__ out) {
  __shared__ float Et[64 * 36];
  __shared__ float Vt[64 * 68];
  const int tid = threadIdx.x;
  const int R0 = blockIdx.x * 32;
  const int D0 = blockIdx.y * 64;
  const int g = blockIdx.z;
  const int i0 = (tid >> 4) << 1;
  const int j0 = (tid & 15) << 2;
  float acc[2][4] = {};
  for (int kc = 0; kc < 4; ++kc) {
    if (kc) __syncthreads();
#pragma unroll
    for (int it = 0; it < 2; ++it) {
      int f4 = tid + it * 256;
      int rr = f4 >> 4;
      int k4 = (f4 & 15) << 2;
      size_t base = ((size_t)g * NG_ + R0 + rr) * NG_ + kc * 64 + k4;
      float4 a = *(const float4*)(E + base);
      Et[(k4 + 0) * 36 + rr] = a.x; Et[(k4 + 1) * 36 + rr] = a.y;
      Et[(k4 + 2) * 36 + rr] = a.z; Et[(k4 + 3) * 36 + rr] = a.w;
    }
#pragma unroll
    for (int it = 0; it < 4; ++it) {
      int f4 = tid + it * 256;
      int kk = f4 >> 4;
      int j4 = (f4 & 15) << 2;
      size_t base = ((size_t)g * NG_ + kc * 64 + kk) * H_ + D0 + j4;
      *(float4*)(Vt + kk * 68 + j4) = *(const float4*)(V + base);
    }
    __syncthreads();
#pragma unroll 8
    for (int k = 0; k < 64; ++k) {
      float e0 = Et[k * 36 + i0];
      float e1 = Et[k * 36 + i0 + 1];
      float4 vv = *(const float4*)(Vt + k * 68 + j0);
      acc[0][0] = fmaf(e0, vv.x, acc[0][0]);
      acc[0][1] = fmaf(e0, vv.y, acc[0][1]);
      acc[0][2] = fmaf(e0, vv.z, acc[0][2]);
      acc[0][3] = fmaf(e0, vv.w, acc[0][3]);
      acc[1][0] = fmaf(e1, vv.x, acc[1][0]);
      acc[1][1] = fmaf(e1, vv.y, acc[1][1]);
      acc[1][2] = fmaf(e1, vv.z, acc[1][2]);
      acc[1][3] = fmaf(e1, vv.w, acc[1][3]);
    }
  }
#pragma unroll
  for (int di = 0; di < 2; ++di) {
    const int n = g * NG_ + R0 + i0 + di;
    const float fct = GF[n] * SCALE_E;
    float4 o = {acc[di][0] * fct, acc[di][1] * fct, acc[di][2] * fct,
                acc[di][3] * fct};
    *(float4*)(out + (size_t)n * H_ + D0 + j0) = o;
  }
}

extern "C" void kernel_launch(void* const* d_in, const int* in_sizes, int n_in,
                              void* d_out, int out_size, void* d_ws,
                              size_t ws_size, hipStream_t stream) {
  const float* node_feat = (const float*)d_in[0];
  const float* positions = (const float*)d_in[1];
  const float* cell = (const float*)d_in[2];
  const float* w = (const float*)d_in[3];
  const float* Wqkv = (const float*)d_in[4];
  const float* Wvg = (const float*)d_in[5];
  const float* bvg = (const float*)d_in[6];
  const float* Whg = (const float*)d_in[7];
  const float* bhg = (const float*)d_in[8];
  const float* Wmg = (const float*)d_in[9];
  const float* bmg = (const float*)d_in[10];
  const int* nvec = (const int*)d_in[11];
  float* out = (float*)d_out;
  float* ws = (float*)d_ws;

  k1_gemm<<<dim3(32, 8), 256, 0, stream>>>(node_feat, Wqkv, Wvg, ws + OFF_QKVG);
  k2_elem<<<512, 256, 0, stream>>>(node_feat, ws + OFF_QKVG, Whg, bhg, Wmg, bmg,
                                   bvg, ws + OFF_AQ, ws + OFF_BQ, ws + OFF_AK,
                                   ws + OFF_BK, ws + OFF_V, ws + OFF_GF,
                                   out + (size_t)NTOT_ * H_);
  k3_frac<<<8, 256, 0, stream>>>(cell, positions, ws + OFF_F);
  k4_trig<<<1024, 256, 0, stream>>>(ws + OFF_F, nvec, w, ws + OFF_C, ws + OFF_S,
                                    ws + OFF_WC, ws + OFF_WS);
  k5_E<<<dim3(8, 4, 8), 256, 0, stream>>>(ws + OFF_AQ, ws + OFF_BQ, ws + OFF_AK,
                                          ws + OFF_BK, ws + OFF_C, ws + OFF_S,
                                          ws + OFF_WC, ws + OFF_WS, ws + OFF_E);
  k6_out<<<dim3(8, 2, 8), 256, 0, stream>>>(ws + OFF_E, ws + OFF_V, ws + OFF_GF,
                                            out);
}

// Round 2
// 35.032 us; speedup vs baseline: 1.5569x; 1.5569x over previous
//
#include <hip/hip_runtime.h>
#include <math.h>

using short8 = __attribute__((ext_vector_type(8))) short;
using f32x4 = __attribute__((ext_vector_type(4))) float;

#define MFMA16(a, b, c) __builtin_amdgcn_mfma_f32_16x16x32_bf16((a), (b), (c), 0, 0, 0)

namespace {
constexpr int G_ = 8;
constexpr int NG_ = 256;
constexpr int H_ = 128;
constexpr int M_ = 128;
constexpr int NTOT_ = 2048;
constexpr float SCALE_E = 0.08838834764831845f / 256.0f;  // (1/sqrt(H))/Ng

// workspace offsets in BYTES
constexpr size_t OFF_QKVG = 0;                    // f32 [2048][512]
constexpr size_t OFF_QA = 4194304;                // bf16 [2048][128] = [aq|bq]
constexpr size_t OFF_KA = OFF_QA + 524288;        // bf16 [2048][128] = [ak|bk]
constexpr size_t OFF_KB = OFF_KA + 524288;        // bf16 [2048][128] = [bk|-ak]
constexpr size_t OFF_VT = OFF_KB + 524288;        // bf16 [8][128][256] (d-major)
constexpr size_t OFF_CT = OFF_VT + 524288;        // bf16 [2048][128] sqrt(w)*cos
constexpr size_t OFF_ST = OFF_CT + 524288;        // bf16 [2048][128] sqrt(w)*sin
constexpr size_t OFF_E  = OFF_ST + 524288;        // bf16 [8][256][256]
constexpr size_t OFF_GF = OFF_E + 1048576;        // f32 [2048]
constexpr size_t OFF_F4 = OFF_GF + 8192;          // f32 [2048][4]
}  // namespace

__device__ __forceinline__ short f2bf(float x) {
  unsigned u = __float_as_uint(x);
  unsigned r = (u + 0x7FFFu + ((u >> 16) & 1u)) >> 16;
  return (short)r;
}
__device__ __forceinline__ float sigmoidf_(float x) { return 1.0f / (1.0f + expf(-x)); }
__device__ __forceinline__ float siluf_(float x) { return x / (1.0f + expf(-x)); }

// ---------------- K1: QKVG = node_feat @ [Wqkv;Wvg]^T via MFMA (fp32 out)
__global__ __launch_bounds__(256) void k1_mfma(
    const float* __restrict__ A, const float* __restrict__ Wqkv,
    const float* __restrict__ Wvg, float* __restrict__ out) {
  __shared__ short lA[128 * 128];
  __shared__ short lB[128 * 128];
  const int tid = threadIdx.x;
  const int n0 = blockIdx.x * 128, c0 = blockIdx.y * 128;
#pragma unroll
  for (int it = 0; it < 8; ++it) {
    int e = tid + it * 256;
    int row = e >> 4, c8 = (e & 15) * 8;
    const float* src = A + (size_t)(n0 + row) * H_ + c8;
    float4 lo = *(const float4*)src, hi = *(const float4*)(src + 4);
    short8 v;
    v[0] = f2bf(lo.x); v[1] = f2bf(lo.y); v[2] = f2bf(lo.z); v[3] = f2bf(lo.w);
    v[4] = f2bf(hi.x); v[5] = f2bf(hi.y); v[6] = f2bf(hi.z); v[7] = f2bf(hi.w);
    int idx = (row * 128 + c8) ^ ((row & 7) << 3);
    *(short8*)&lA[idx] = v;
    int wr = c0 + row;
    const float* bs =
        (wr < 384 ? Wqkv + (size_t)wr * H_ : Wvg + (size_t)(wr - 384) * H_) + c8;
    float4 bl = *(const float4*)bs, bh = *(const float4*)(bs + 4);
    short8 bv;
    bv[0] = f2bf(bl.x); bv[1] = f2bf(bl.y); bv[2] = f2bf(bl.z); bv[3] = f2bf(bl.w);
    bv[4] = f2bf(bh.x); bv[5] = f2bf(bh.y); bv[6] = f2bf(bh.z); bv[7] = f2bf(bh.w);
    *(short8*)&lB[idx] = bv;
  }
  __syncthreads();
  const int wid = tid >> 6, lane = tid & 63;
  const int wr = (wid >> 1) * 64, wc = (wid & 1) * 64;
  const int frow = lane & 15, kq = (lane >> 4) * 8;
  f32x4 acc[4][4] = {};
#pragma unroll
  for (int ks = 0; ks < 4; ++ks) {
    int kk = ks * 32 + kq;
    short8 a[4], b[4];
#pragma unroll
    for (int i = 0; i < 4; ++i) {
      int ra = wr + i * 16 + frow;
      a[i] = *(short8*)&lA[(ra * 128 + kk) ^ ((ra & 7) << 3)];
      int rb = wc + i * 16 + frow;
      b[i] = *(short8*)&lB[(rb * 128 + kk) ^ ((rb & 7) << 3)];
    }
#pragma unroll
    for (int i = 0; i < 4; ++i)
#pragma unroll
      for (int j = 0; j < 4; ++j) acc[i][j] = MFMA16(a[i], b[j], acc[i][j]);
  }
  const int orow = (lane >> 4) * 4, ocol = lane & 15;
#pragma unroll
  for (int i = 0; i < 4; ++i)
#pragma unroll
    for (int j = 0; j < 4; ++j) {
      int c = c0 + wc + j * 16 + ocol;
#pragma unroll
      for (int r = 0; r < 4; ++r) {
        int n = n0 + wr + i * 16 + orow + r;
        out[(size_t)n * 512 + c] = acc[i][j][r];
      }
    }
}

// ---------------- K2: activations -> QA/KA/KB bf16, gates
__global__ __launch_bounds__(256) void k2_elem(
    const float* __restrict__ scalars, const float* __restrict__ qkvg,
    const float* __restrict__ Whg, const float* __restrict__ bhg,
    const float* __restrict__ Wmg, const float* __restrict__ bmg,
    short* __restrict__ QA, short* __restrict__ KA, short* __restrict__ KB,
    float* __restrict__ GF, float* __restrict__ out_gate) {
  const int wave = threadIdx.x >> 6;
  const int lane = threadIdx.x & 63;
  const int n = blockIdx.x * 4 + wave;
  const float* row = qkvg + (size_t)n * 512;
  float q0 = siluf_(row[2 * lane]);
  float q1 = siluf_(row[2 * lane + 1]);
  float k0 = siluf_(row[128 + 2 * lane]);
  float k1 = siluf_(row[128 + 2 * lane + 1]);
  const size_t b = (size_t)n * 128;
  QA[b + lane] = f2bf(q0);
  QA[b + 64 + lane] = f2bf(q1);
  KA[b + lane] = f2bf(k0);
  KA[b + 64 + lane] = f2bf(k1);
  KB[b + lane] = f2bf(k1);
  KB[b + 64 + lane] = f2bf(-k0);
  const float* srow = scalars + (size_t)n * H_;
  float s0 = srow[lane], s1 = srow[64 + lane];
  float hg = s0 * Whg[lane] + s1 * Whg[64 + lane];
  float mg = s0 * Wmg[lane] + s1 * Wmg[64 + lane];
#pragma unroll
  for (int off = 32; off; off >>= 1) {
    hg += __shfl_down(hg, off, 64);
    mg += __shfl_down(mg, off, 64);
  }
  if (lane == 0) {
    GF[n] = 1.0f + 0.2f * tanhf(hg + bhg[0]);
    out_gate[n] = sigmoidf_(mg + bmg[0]);
  }
}

// ---------------- K2V: gated V, transposed to [g][d][n] bf16
__global__ __launch_bounds__(256) void k2v(
    const float* __restrict__ qkvg, const float* __restrict__ bvg,
    short* __restrict__ Vt) {
  __shared__ short lv[128 * 66];
  const int t = threadIdx.x;
  const int n0 = blockIdx.x * 64;
  const int g = blockIdx.y;
#pragma unroll
  for (int it = 0; it < 32; ++it) {
    int e = t + it * 256;
    int n = e >> 7, d = e & 127;
    const float* row = qkvg + ((size_t)(g * NG_ + n0 + n)) * 512;
    float val = row[256 + d] * sigmoidf_(row[384 + d] + bvg[d]);
    lv[d * 66 + n] = f2bf(val);
  }
  __syncthreads();
#pragma unroll
  for (int it = 0; it < 32; ++it) {
    int e = t + it * 256;
    int d = e >> 6, nn = e & 63;
    Vt[((size_t)g * 128 + d) * 256 + n0 + nn] = lv[d * 66 + nn];
  }
}

// ---------------- K3: fractional coords
__global__ __launch_bounds__(256) void k3_frac(
    const float* __restrict__ cell, const float* __restrict__ pos,
    float* __restrict__ F4) {
  const int g = blockIdx.x;
  const int nl = threadIdx.x;
  const float* cg = cell + (size_t)g * 9;
  float A00 = cg[0], A01 = cg[3], A02 = cg[6];
  float A10 = cg[1], A11 = cg[4], A12 = cg[7];
  float A20 = cg[2], A21 = cg[5], A22 = cg[8];
  float b00 = A11 * A22 - A12 * A21;
  float b01 = A02 * A21 - A01 * A22;
  float b02 = A01 * A12 - A02 * A11;
  float b10 = A12 * A20 - A10 * A22;
  float b11 = A00 * A22 - A02 * A20;
  float b12 = A02 * A10 - A00 * A12;
  float b20 = A10 * A21 - A11 * A20;
  float b21 = A01 * A20 - A00 * A21;
  float b22 = A00 * A11 - A01 * A10;
  float det = A00 * b00 + A01 * b10 + A02 * b20;
  float inv = 1.0f / det;
  const int node = g * NG_ + nl;
  float p0 = pos[(size_t)node * 3 + 0];
  float p1 = pos[(size_t)node * 3 + 1];
  float p2 = pos[(size_t)node * 3 + 2];
  float f0 = (b00 * p0 + b01 * p1 + b02 * p2) * inv;
  float f1 = (b10 * p0 + b11 * p1 + b12 * p2) * inv;
  float f2 = (b20 * p0 + b21 * p1 + b22 * p2) * inv;
  f0 -= floorf(f0); f1 -= floorf(f1); f2 -= floorf(f2);
  F4[(size_t)node * 4 + 0] = f0;
  F4[(size_t)node * 4 + 1] = f1;
  F4[(size_t)node * 4 + 2] = f2;
  F4[(size_t)node * 4 + 3] = 0.0f;
}

// ---------------- K4: trig tables Ct,St = sqrt(w)*{cos,sin}, [node][m] bf16
__global__ __launch_bounds__(256) void k4_trig(
    const float* __restrict__ F4, const int* __restrict__ nvec,
    const float* __restrict__ w, short* __restrict__ Ct, short* __restrict__ St) {
  const int t = threadIdx.x;
  const int g = blockIdx.y;
  const int n = blockIdx.x * 16 + (t >> 4);
  const int m0 = (t & 15) * 8;
  const float* f = F4 + ((size_t)g * NG_ + n) * 4;
  float f0 = f[0], f1 = f[1], f2 = f[2];
  short8 pc, ps;
#pragma unroll
  for (int i = 0; i < 8; ++i) {
    const int m = m0 + i;
    const int* nv = nvec + ((size_t)g * M_ + m) * 3;
    float dot = f0 * (float)nv[0] + f1 * (float)nv[1] + f2 * (float)nv[2];
    float tr = dot - floorf(dot);
    float sn = __builtin_amdgcn_sinf(tr);
    float cs = __builtin_amdgcn_cosf(tr);
    float sq = sqrtf(w[g * M_ + m]);
    pc[i] = f2bf(sq * cs);
    ps[i] = f2bf(sq * sn);
  }
  const size_t b = ((size_t)g * NG_ + n) * M_ + m0;
  *(short8*)&Ct[b] = pc;
  *(short8*)&St[b] = ps;
}

// ---------------- K5: E = (QA.KA^T)*(Ct.Ct^T + St.St^T) + (QA.KB^T)*(St.Ct^T - Ct.St^T)
__global__ __launch_bounds__(256) void k5_mfma(
    const short* __restrict__ QA, const short* __restrict__ KA,
    const short* __restrict__ KB, const short* __restrict__ Ct,
    const short* __restrict__ St, short* __restrict__ E) {
  __shared__ short s1[64 * 128];
  __shared__ short s2[64 * 128];
  __shared__ short s3[64 * 128];
  __shared__ short s4[64 * 128];
  const int tid = threadIdx.x;
  const int R0 = blockIdx.x * 64, C0 = blockIdx.y * 64;
  const int g = blockIdx.z;
  const int gn = g * NG_;
  const int wid = tid >> 6, lane = tid & 63;
  const int wr = (wid >> 1) * 32, wc = (wid & 1) * 32;
  const int frow = lane & 15, kq = (lane >> 4) * 8;

  // phase 1 staging: QA rows, KA cols, KB cols
#pragma unroll
  for (int it = 0; it < 4; ++it) {
    int e = tid + it * 256;
    int row = e >> 4, c8 = (e & 15) * 8;
    int idx = (row * 128 + c8) ^ ((row & 7) << 3);
    *(short8*)&s1[idx] = *(const short8*)&QA[((size_t)(gn + R0 + row)) * 128 + c8];
    *(short8*)&s2[idx] = *(const short8*)&KA[((size_t)(gn + C0 + row)) * 128 + c8];
    *(short8*)&s3[idx] = *(const short8*)&KB[((size_t)(gn + C0 + row)) * 128 + c8];
  }
  __syncthreads();
  f32x4 gc[2][2] = {}, gs[2][2] = {};
#pragma unroll
  for (int ks = 0; ks < 4; ++ks) {
    int kk = ks * 32 + kq;
    short8 a[2], ka[2], kb[2];
#pragma unroll
    for (int i = 0; i < 2; ++i) {
      int ra = wr + i * 16 + frow;
      a[i] = *(short8*)&s1[(ra * 128 + kk) ^ ((ra & 7) << 3)];
      int rb = wc + i * 16 + frow;
      ka[i] = *(short8*)&s2[(rb * 128 + kk) ^ ((rb & 7) << 3)];
      kb[i] = *(short8*)&s3[(rb * 128 + kk) ^ ((rb & 7) << 3)];
    }
#pragma unroll
    for (int i = 0; i < 2; ++i)
#pragma unroll
      for (int j = 0; j < 2; ++j) {
        gc[i][j] = MFMA16(a[i], ka[j], gc[i][j]);
        gs[i][j] = MFMA16(a[i], kb[j], gs[i][j]);
      }
  }
  __syncthreads();
  // phase 2 staging: Ct/St rows (R0), Ct/St cols (C0)
#pragma unroll
  for (int it = 0; it < 4; ++it) {
    int e = tid + it * 256;
    int row = e >> 4, c8 = (e & 15) * 8;
    int idx = (row * 128 + c8) ^ ((row & 7) << 3);
    *(short8*)&s1[idx] = *(const short8*)&Ct[((size_t)(gn + R0 + row)) * 128 + c8];
    *(short8*)&s2[idx] = *(const short8*)&St[((size_t)(gn + R0 + row)) * 128 + c8];
    *(short8*)&s3[idx] = *(const short8*)&Ct[((size_t)(gn + C0 + row)) * 128 + c8];
    *(short8*)&s4[idx] = *(const short8*)&St[((size_t)(gn + C0 + row)) * 128 + c8];
  }
  __syncthreads();
  f32x4 cc[2][2] = {}, cs1[2][2] = {}, cs2[2][2] = {};
#pragma unroll
  for (int ks = 0; ks < 4; ++ks) {
    int kk = ks * 32 + kq;
    short8 ca[2], sa[2], cb[2], sb[2];
#pragma unroll
    for (int i = 0; i < 2; ++i) {
      int ra = wr + i * 16 + frow;
      ca[i] = *(short8*)&s1[(ra * 128 + kk) ^ ((ra & 7) << 3)];
      sa[i] = *(short8*)&s2[(ra * 128 + kk) ^ ((ra & 7) << 3)];
      int rb = wc + i * 16 + frow;
      cb[i] = *(short8*)&s3[(rb * 128 + kk) ^ ((rb & 7) << 3)];
      sb[i] = *(short8*)&s4[(rb * 128 + kk) ^ ((rb & 7) << 3)];
    }
#pragma unroll
    for (int i = 0; i < 2; ++i)
#pragma unroll
      for (int j = 0; j < 2; ++j) {
        cc[i][j] = MFMA16(ca[i], cb[j], cc[i][j]);
        cc[i][j] = MFMA16(sa[i], sb[j], cc[i][j]);
        cs1[i][j] = MFMA16(sa[i], cb[j], cs1[i][j]);
        cs2[i][j] = MFMA16(ca[i], sb[j], cs2[i][j]);
      }
  }
  const int orow = (lane >> 4) * 4, ocol = lane & 15;
#pragma unroll
  for (int i = 0; i < 2; ++i)
#pragma unroll
    for (int j = 0; j < 2; ++j) {
      int col = C0 + wc + j * 16 + ocol;
#pragma unroll
      for (int r = 0; r < 4; ++r) {
        int row = R0 + wr + i * 16 + orow + r;
        float e = gc[i][j][r] * cc[i][j][r] +
                  gs[i][j][r] * (cs1[i][j][r] - cs2[i][j][r]);
        E[((size_t)g * NG_ + row) * NG_ + col] = f2bf(e);
      }
    }
}

// ---------------- K6: update = GF*SCALE*(E @ V)
__global__ __launch_bounds__(128) void k6_mfma(
    const short* __restrict__ E, const short* __restrict__ Vt,
    const float* __restrict__ GF, float* __restrict__ out) {
  __shared__ short lE[64 * 256];
  __shared__ short lV[64 * 256];
  const int tid = threadIdx.x;
  const int N0 = blockIdx.x * 64, D0 = blockIdx.y * 64;
  const int g = blockIdx.z;
  const int wid = tid >> 6, lane = tid & 63;
  const int wr = wid * 32;
  const int frow = lane & 15, kq = (lane >> 4) * 8;
#pragma unroll
  for (int it = 0; it < 16; ++it) {
    int e = tid + it * 128;
    int row = e >> 5, c8 = (e & 31) * 8;
    int idx = (row * 256 + c8) ^ ((row & 7) << 3);
    *(short8*)&lE[idx] = *(const short8*)&E[((size_t)g * NG_ + N0 + row) * 256 + c8];
    *(short8*)&lV[idx] = *(const short8*)&Vt[((size_t)g * 128 + D0 + row) * 256 + c8];
  }
  __syncthreads();
  f32x4 acc[2][4] = {};
#pragma unroll
  for (int ks = 0; ks < 8; ++ks) {
    int kk = ks * 32 + kq;
    short8 a[2], b[4];
#pragma unroll
    for (int i = 0; i < 2; ++i) {
      int ra = wr + i * 16 + frow;
      a[i] = *(short8*)&lE[(ra * 256 + kk) ^ ((ra & 7) << 3)];
    }
#pragma unroll
    for (int j = 0; j < 4; ++j) {
      int rb = j * 16 + frow;
      b[j] = *(short8*)&lV[(rb * 256 + kk) ^ ((rb & 7) << 3)];
    }
#pragma unroll
    for (int i = 0; i < 2; ++i)
#pragma unroll
      for (int j = 0; j < 4; ++j) acc[i][j] = MFMA16(a[i], b[j], acc[i][j]);
  }
  const int orow = (lane >> 4) * 4, ocol = lane & 15;
#pragma unroll
  for (int i = 0; i < 2; ++i)
#pragma unroll
    for (int r = 0; r < 4; ++r) {
      int gnode = g * NG_ + N0 + wr + i * 16 + orow + r;
      float fct = GF[gnode] * SCALE_E;
#pragma unroll
      for (int j = 0; j < 4; ++j) {
        out[(size_t)gnode * H_ + D0 + j * 16 + ocol] = acc[i][j][r] * fct;
      }
    }
}

extern "C" void kernel_launch(void* const* d_in, const int* in_sizes, int n_in,
                              void* d_out, int out_size, void* d_ws,
                              size_t ws_size, hipStream_t stream) {
  const float* node_feat = (const float*)d_in[0];
  const float* positions = (const float*)d_in[1];
  const float* cell = (const float*)d_in[2];
  const float* w = (const float*)d_in[3];
  const float* Wqkv = (const float*)d_in[4];
  const float* Wvg = (const float*)d_in[5];
  const float* bvg = (const float*)d_in[6];
  const float* Whg = (const float*)d_in[7];
  const float* bhg = (const float*)d_in[8];
  const float* Wmg = (const float*)d_in[9];
  const float* bmg = (const float*)d_in[10];
  const int* nvec = (const int*)d_in[11];
  float* out = (float*)d_out;
  char* ws = (char*)d_ws;

  float* QKVG = (float*)(ws + OFF_QKVG);
  short* QA = (short*)(ws + OFF_QA);
  short* KA = (short*)(ws + OFF_KA);
  short* KB = (short*)(ws + OFF_KB);
  short* VT = (short*)(ws + OFF_VT);
  short* CT = (short*)(ws + OFF_CT);
  short* ST = (short*)(ws + OFF_ST);
  short* E = (short*)(ws + OFF_E);
  float* GF = (float*)(ws + OFF_GF);
  float* F4 = (float*)(ws + OFF_F4);

  k1_mfma<<<dim3(16, 4), 256, 0, stream>>>(node_feat, Wqkv, Wvg, QKVG);
  k3_frac<<<8, 256, 0, stream>>>(cell, positions, F4);
  k4_trig<<<dim3(16, 8), 256, 0, stream>>>(F4, nvec, w, CT, ST);
  k2_elem<<<512, 256, 0, stream>>>(node_feat, QKVG, Whg, bhg, Wmg, bmg, QA, KA,
                                   KB, GF, out + (size_t)NTOT_ * H_);
  k2v<<<dim3(4, 8), 256, 0, stream>>>(QKVG, bvg, VT);
  k5_mfma<<<dim3(4, 4, 8), 256, 0, stream>>>(QA, KA, KB, CT, ST, E);
  k6_mfma<<<dim3(4, 2, 8), 128, 0, stream>>>(E, VT, GF, out);
}

// Round 3
// 28.715 us; speedup vs baseline: 1.8994x; 1.2200x over previous
//
#include <hip/hip_runtime.h>
#include <math.h>

using short8 = __attribute__((ext_vector_type(8))) short;
using f32x4 = __attribute__((ext_vector_type(4))) float;

#define MFMA16(a, b, c) __builtin_amdgcn_mfma_f32_16x16x32_bf16((a), (b), (c), 0, 0, 0)

namespace {
constexpr int NG_ = 256;
constexpr int H_ = 128;
constexpr int NTOT_ = 2048;
constexpr float SCALE_E = 0.08838834764831845f / 256.0f;  // (1/sqrt(H))/Ng

// workspace offsets in BYTES
constexpr size_t OFF_QA = 0;               // bf16 [2048][128] = [aq|bq]
constexpr size_t OFF_KA = 524288;          // bf16 [2048][128] = [ak|bk]
constexpr size_t OFF_VT = 1048576;         // bf16 [8][128][256] (d-major)
constexpr size_t OFF_CT = 1572864;         // bf16 [2048][128] sqrt(w)*cos
constexpr size_t OFF_ST = 2097152;         // bf16 [2048][128] sqrt(w)*sin
constexpr size_t OFF_E  = 2621440;         // bf16 [8][256][256]
constexpr size_t OFF_GF = 3670016;         // f32 [2048]
}  // namespace

__device__ __forceinline__ short f2bf(float x) {
  unsigned u = __float_as_uint(x);
  unsigned r = (u + 0x7FFFu + ((u >> 16) & 1u)) >> 16;
  return (short)r;
}
__device__ __forceinline__ float bf2f(short x) {
  return __uint_as_float(((unsigned)(unsigned short)x) << 16);
}
__device__ __forceinline__ float sigmoidf_(float x) { return 1.0f / (1.0f + expf(-x)); }
__device__ __forceinline__ float siluf_(float x) { return x / (1.0f + expf(-x)); }

__device__ __forceinline__ short8 neg8(short8 x) {
  short8 r;
#pragma unroll
  for (int i = 0; i < 8; ++i) r[i] = (short)(x[i] ^ (short)0x8000);
  return r;
}
// fragment read from a [rows][128] bf16 LDS tile, XOR-swizzled
__device__ __forceinline__ short8 ldf(const short* buf, int row, int kk) {
  return *(const short8*)&buf[(row * 128 + kk) ^ ((row & 7) << 3)];
}

// ================= K_prep: fused GEMM+activations (32 blocks) + trig (64 blocks)
__global__ __launch_bounds__(512) void k_prep(
    const float* __restrict__ nf, const float* __restrict__ Wqkv,
    const float* __restrict__ Wvg, const float* __restrict__ bvg,
    const float* __restrict__ Whg, const float* __restrict__ bhg,
    const float* __restrict__ Wmg, const float* __restrict__ bmg,
    const float* __restrict__ cell, const float* __restrict__ pos,
    const int* __restrict__ nvec, const float* __restrict__ w,
    short* __restrict__ QA, short* __restrict__ KA, short* __restrict__ VT,
    short* __restrict__ CT, short* __restrict__ ST, float* __restrict__ GF,
    float* __restrict__ out_gate) {
  __shared__ short smem[49152];  // 96 KB
  const int tid = threadIdx.x;
  const int bid = blockIdx.x;
  if (bid < 32) {
    // ---- GEMM block: 128 rows x 256 cols, K=128
    short* lA = smem;          // 128x128
    short* lB = smem + 16384;  // 256x128
    const int r_tile = bid >> 1, h = bid & 1;
    const int n0 = r_tile * 128, c0 = h * 256;
#pragma unroll
    for (int it = 0; it < 4; ++it) {
      int e = tid + it * 512;
      int row = e >> 4, c8 = (e & 15) * 8;
      const float* src = nf + (size_t)(n0 + row) * H_ + c8;
      float4 lo = *(const float4*)src, hi = *(const float4*)(src + 4);
      short8 v;
      v[0] = f2bf(lo.x); v[1] = f2bf(lo.y); v[2] = f2bf(lo.z); v[3] = f2bf(lo.w);
      v[4] = f2bf(hi.x); v[5] = f2bf(hi.y); v[6] = f2bf(hi.z); v[7] = f2bf(hi.w);
      *(short8*)&lA[(row * 128 + c8) ^ ((row & 7) << 3)] = v;
    }
#pragma unroll
    for (int it = 0; it < 8; ++it) {
      int e = tid + it * 512;
      int row = e >> 4, c8 = (e & 15) * 8;
      int wr_g = c0 + row;
      const float* src =
          (wr_g < 384 ? Wqkv + (size_t)wr_g * H_ : Wvg + (size_t)(wr_g - 384) * H_) + c8;
      float4 lo = *(const float4*)src, hi = *(const float4*)(src + 4);
      short8 v;
      v[0] = f2bf(lo.x); v[1] = f2bf(lo.y); v[2] = f2bf(lo.z); v[3] = f2bf(lo.w);
      v[4] = f2bf(hi.x); v[5] = f2bf(hi.y); v[6] = f2bf(hi.z); v[7] = f2bf(hi.w);
      *(short8*)&lB[(row * 128 + c8) ^ ((row & 7) << 3)] = v;
    }
    __syncthreads();
    const int wid = tid >> 6, lane = tid & 63;
    const int wrow = (wid >> 2) * 64, wcol = (wid & 3) * 64;
    const int frow = lane & 15, kq = (lane >> 4) * 8;
    f32x4 acc[4][4] = {};
#pragma unroll
    for (int ks = 0; ks < 4; ++ks) {
      int kk = ks * 32 + kq;
      short8 a[4], b[4];
#pragma unroll
      for (int i = 0; i < 4; ++i) {
        a[i] = ldf(lA, wrow + i * 16 + frow, kk);
        b[i] = ldf(lB, wcol + i * 16 + frow, kk);
      }
#pragma unroll
      for (int i = 0; i < 4; ++i)
#pragma unroll
        for (int j = 0; j < 4; ++j) acc[i][j] = MFMA16(a[i], b[j], acc[i][j]);
    }
    const int orow = (lane >> 4) * 4, ocol = lane & 15;
    __syncthreads();  // before any lB reuse
    if (h == 0) {
      // q (cols 0..127) -> QA, k (128..255) -> KA; silu + deinterleave
#pragma unroll
      for (int i = 0; i < 4; ++i)
#pragma unroll
        for (int j = 0; j < 4; ++j) {
          int c = wcol + j * 16 + ocol;
#pragma unroll
          for (int r = 0; r < 4; ++r) {
            int node = n0 + wrow + i * 16 + orow + r;
            float val = siluf_(acc[i][j][r]);
            if (c < 128)
              QA[(size_t)node * 128 + (c & 1) * 64 + (c >> 1)] = f2bf(val);
            else {
              int ck = c - 128;
              KA[(size_t)node * 128 + (ck & 1) * 64 + (ck >> 1)] = f2bf(val);
            }
          }
        }
    } else {
      // v (local cols 0..127) gated by sigmoid(vg local 128..255 + bvg)
      short* gate_sh = lB;  // 128x128 bf16
      if (wcol >= 128) {
#pragma unroll
        for (int i = 0; i < 4; ++i)
#pragma unroll
          for (int j = 0; j < 4; ++j) {
            int d = wcol - 128 + j * 16 + ocol;
#pragma unroll
            for (int r = 0; r < 4; ++r) {
              int nl = wrow + i * 16 + orow + r;
              gate_sh[nl * 128 + d] = f2bf(sigmoidf_(acc[i][j][r] + bvg[d]));
            }
          }
      }
      __syncthreads();
      if (wcol < 128) {
        const int g_idx = n0 >> 8, half = (n0 >> 7) & 1;
#pragma unroll
        for (int i = 0; i < 4; ++i)
#pragma unroll
          for (int j = 0; j < 4; ++j) {
            int d = wcol + j * 16 + ocol;
#pragma unroll
            for (int r = 0; r < 4; ++r) {
              int nl = wrow + i * 16 + orow + r;
              float gate = bf2f(gate_sh[nl * 128 + d]);
              VT[((size_t)(g_idx * 128 + d)) * 256 + half * 128 + nl] =
                  f2bf(acc[i][j][r] * gate);
            }
          }
      }
      // per-node gates from bf16 scalars in lA
      if (tid < 128) {
        int nl = tid;
        float hg = 0.f, mg = 0.f;
#pragma unroll 8
        for (int c = 0; c < 128; ++c) {
          float s = bf2f(lA[((nl * 128 + (c & ~7)) ^ ((nl & 7) << 3)) + (c & 7)]);
          hg += s * Whg[c];
          mg += s * Wmg[c];
        }
        int node = n0 + nl;
        GF[node] = 1.0f + 0.2f * tanhf(hg + bhg[0]);
        out_gate[node] = sigmoidf_(mg + bmg[0]);
      }
    }
  } else {
    // ---- trig block: group g, 32 nodes, all 128 m
    const int b = bid - 32;
    const int g = b >> 3, n0 = (b & 7) * 32;
    float* f_sh = (float*)smem;                   // 32*4 f32
    int* nv_sh = (int*)((char*)smem + 512);       // 128*3 int
    float* w_sh = (float*)((char*)smem + 2048);   // 128 f32
    if (tid < 32) {
      const float* cg = cell + (size_t)g * 9;
      float A00 = cg[0], A01 = cg[3], A02 = cg[6];
      float A10 = cg[1], A11 = cg[4], A12 = cg[7];
      float A20 = cg[2], A21 = cg[5], A22 = cg[8];
      float b00 = A11 * A22 - A12 * A21;
      float b01 = A02 * A21 - A01 * A22;
      float b02 = A01 * A12 - A02 * A11;
      float b10 = A12 * A20 - A10 * A22;
      float b11 = A00 * A22 - A02 * A20;
      float b12 = A02 * A10 - A00 * A12;
      float b20 = A10 * A21 - A11 * A20;
      float b21 = A01 * A20 - A00 * A21;
      float b22 = A00 * A11 - A01 * A10;
      float det = A00 * b00 + A01 * b10 + A02 * b20;
      float inv = 1.0f / det;
      const int node = g * NG_ + n0 + tid;
      float p0 = pos[(size_t)node * 3 + 0];
      float p1 = pos[(size_t)node * 3 + 1];
      float p2 = pos[(size_t)node * 3 + 2];
      float f0 = (b00 * p0 + b01 * p1 + b02 * p2) * inv;
      float f1 = (b10 * p0 + b11 * p1 + b12 * p2) * inv;
      float f2 = (b20 * p0 + b21 * p1 + b22 * p2) * inv;
      f_sh[tid * 4 + 0] = f0 - floorf(f0);
      f_sh[tid * 4 + 1] = f1 - floorf(f1);
      f_sh[tid * 4 + 2] = f2 - floorf(f2);
    }
    if (tid < 128) {
      nv_sh[tid * 3 + 0] = nvec[((size_t)g * 128 + tid) * 3 + 0];
      nv_sh[tid * 3 + 1] = nvec[((size_t)g * 128 + tid) * 3 + 1];
      nv_sh[tid * 3 + 2] = nvec[((size_t)g * 128 + tid) * 3 + 2];
      w_sh[tid] = sqrtf(w[(size_t)g * 128 + tid]);
    }
    __syncthreads();
    const int n_l = tid >> 4, m0 = (tid & 15) * 8;
    float f0 = f_sh[n_l * 4 + 0], f1 = f_sh[n_l * 4 + 1], f2 = f_sh[n_l * 4 + 2];
    short8 pc, ps;
#pragma unroll
    for (int i = 0; i < 8; ++i) {
      int m = m0 + i;
      float dot = f0 * (float)nv_sh[m * 3] + f1 * (float)nv_sh[m * 3 + 1] +
                  f2 * (float)nv_sh[m * 3 + 2];
      float tr = dot - floorf(dot);
      float sn = __builtin_amdgcn_sinf(tr);
      float cs = __builtin_amdgcn_cosf(tr);
      float sq = w_sh[m];
      pc[i] = f2bf(sq * cs);
      ps[i] = f2bf(sq * sn);
    }
    const int node = g * NG_ + n0 + n_l;
    *(short8*)&CT[(size_t)node * 128 + m0] = pc;
    *(short8*)&ST[(size_t)node * 128 + m0] = ps;
  }
}

// ================= K_E: E = (QA.KA^T)*(X.X^T parts) with complex packing
__global__ __launch_bounds__(256) void k_E(
    const short* __restrict__ QA, const short* __restrict__ KA,
    const short* __restrict__ Ct, const short* __restrict__ St,
    short* __restrict__ E) {
  __shared__ short sm[49152];
  short* tQA = sm;
  short* tKA = sm + 8192;
  short* tCr = sm + 16384;
  short* tSr = sm + 24576;
  short* tCc = sm + 32768;
  short* tSc = sm + 40960;
  const int tid = threadIdx.x;
  const int R0 = blockIdx.x * 64, C0 = blockIdx.y * 64;
  const int g = blockIdx.z, gn = g * NG_;
#pragma unroll
  for (int it = 0; it < 4; ++it) {
    int e = tid + it * 256;
    int row = e >> 4, c8 = (e & 15) * 8;
    int idx = (row * 128 + c8) ^ ((row & 7) << 3);
    *(short8*)&tQA[idx] = *(const short8*)&QA[(size_t)(gn + R0 + row) * 128 + c8];
    *(short8*)&tKA[idx] = *(const short8*)&KA[(size_t)(gn + C0 + row) * 128 + c8];
    *(short8*)&tCr[idx] = *(const short8*)&Ct[(size_t)(gn + R0 + row) * 128 + c8];
    *(short8*)&tSr[idx] = *(const short8*)&St[(size_t)(gn + R0 + row) * 128 + c8];
    *(short8*)&tCc[idx] = *(const short8*)&Ct[(size_t)(gn + C0 + row) * 128 + c8];
    *(short8*)&tSc[idx] = *(const short8*)&St[(size_t)(gn + C0 + row) * 128 + c8];
  }
  __syncthreads();
  const int wid = tid >> 6, lane = tid & 63;
  const int wr = (wid >> 1) * 32, wc = (wid & 1) * 32;
  const int frow = lane & 15, kq = (lane >> 4) * 8;
  f32x4 gc[2][2] = {}, gs[2][2] = {}, cc[2][2] = {}, cs[2][2] = {};
  // phase 1: Gram over channels, KB derived from KA (half-swap + negate)
#pragma unroll
  for (int ks = 0; ks < 4; ++ks) {
    int kk = ks * 32 + kq, kk2 = (kk + 64) & 127;
    short8 aq[2], ka[2], kb[2];
#pragma unroll
    for (int i = 0; i < 2; ++i) {
      aq[i] = ldf(tQA, wr + i * 16 + frow, kk);
      ka[i] = ldf(tKA, wc + i * 16 + frow, kk);
      short8 t = ldf(tKA, wc + i * 16 + frow, kk2);
      kb[i] = (ks >= 2) ? neg8(t) : t;
    }
#pragma unroll
    for (int i = 0; i < 2; ++i)
#pragma unroll
      for (int j = 0; j < 2; ++j) {
        gc[i][j] = MFMA16(aq[i], ka[j], gc[i][j]);
        gs[i][j] = MFMA16(aq[i], kb[j], gs[i][j]);
      }
  }
  // phase 2: trig Grams via X=[C|S], Y=[S|-C], K=256
#pragma unroll
  for (int ks = 0; ks < 8; ++ks) {
    const bool lo = ks < 4;
    int kk = (ks & 3) * 32 + kq;
    short8 xr[2], yr[2], xc[2];
#pragma unroll
    for (int i = 0; i < 2; ++i) {
      short8 cr = ldf(tCr, wr + i * 16 + frow, kk);
      short8 sr = ldf(tSr, wr + i * 16 + frow, kk);
      xr[i] = lo ? cr : sr;
      yr[i] = lo ? sr : neg8(cr);
    }
#pragma unroll
    for (int j = 0; j < 2; ++j) xc[j] = ldf(lo ? tCc : tSc, wc + j * 16 + frow, kk);
#pragma unroll
    for (int i = 0; i < 2; ++i)
#pragma unroll
      for (int j = 0; j < 2; ++j) {
        cc[i][j] = MFMA16(xr[i], xc[j], cc[i][j]);
        cs[i][j] = MFMA16(yr[i], xc[j], cs[i][j]);
      }
  }
  const int orow = (lane >> 4) * 4, ocol = lane & 15;
#pragma unroll
  for (int i = 0; i < 2; ++i)
#pragma unroll
    for (int j = 0; j < 2; ++j) {
      int col = C0 + wc + j * 16 + ocol;
#pragma unroll
      for (int r = 0; r < 4; ++r) {
        int row = R0 + wr + i * 16 + orow + r;
        float e = gc[i][j][r] * cc[i][j][r] + gs[i][j][r] * cs[i][j][r];
        E[(size_t)(gn + row) * NG_ + col] = f2bf(e);
      }
    }
}

// ================= K_D: update = GF*SCALE*(E @ V)
__global__ __launch_bounds__(128) void k_out(
    const short* __restrict__ E, const short* __restrict__ Vt,
    const float* __restrict__ GF, float* __restrict__ out) {
  __shared__ short lE[64 * 256];
  __shared__ short lV[64 * 256];
  const int tid = threadIdx.x;
  const int N0 = blockIdx.x * 64, D0 = blockIdx.y * 64;
  const int g = blockIdx.z;
  const int wid = tid >> 6, lane = tid & 63;
  const int wr = wid * 32;
  const int frow = lane & 15, kq = (lane >> 4) * 8;
#pragma unroll
  for (int it = 0; it < 16; ++it) {
    int e = tid + it * 128;
    int row = e >> 5, c8 = (e & 31) * 8;
    int idx = (row * 256 + c8) ^ ((row & 7) << 3);
    *(short8*)&lE[idx] = *(const short8*)&E[((size_t)g * NG_ + N0 + row) * 256 + c8];
    *(short8*)&lV[idx] = *(const short8*)&Vt[((size_t)g * 128 + D0 + row) * 256 + c8];
  }
  __syncthreads();
  f32x4 acc[2][4] = {};
#pragma unroll
  for (int ks = 0; ks < 8; ++ks) {
    int kk = ks * 32 + kq;
    short8 a[2], b[4];
#pragma unroll
    for (int i = 0; i < 2; ++i) {
      int ra = wr + i * 16 + frow;
      a[i] = *(short8*)&lE[(ra * 256 + kk) ^ ((ra & 7) << 3)];
    }
#pragma unroll
    for (int j = 0; j < 4; ++j) {
      int rb = j * 16 + frow;
      b[j] = *(short8*)&lV[(rb * 256 + kk) ^ ((rb & 7) << 3)];
    }
#pragma unroll
    for (int i = 0; i < 2; ++i)
#pragma unroll
      for (int j = 0; j < 4; ++j) acc[i][j] = MFMA16(a[i], b[j], acc[i][j]);
  }
  const int orow = (lane >> 4) * 4, ocol = lane & 15;
#pragma unroll
  for (int i = 0; i < 2; ++i)
#pragma unroll
    for (int r = 0; r < 4; ++r) {
      int gnode = g * NG_ + N0 + wr + i * 16 + orow + r;
      float fct = GF[gnode] * SCALE_E;
#pragma unroll
      for (int j = 0; j < 4; ++j) {
        out[(size_t)gnode * H_ + D0 + j * 16 + ocol] = acc[i][j][r] * fct;
      }
    }
}

extern "C" void kernel_launch(void* const* d_in, const int* in_sizes, int n_in,
                              void* d_out, int out_size, void* d_ws,
                              size_t ws_size, hipStream_t stream) {
  const float* node_feat = (const float*)d_in[0];
  const float* positions = (const float*)d_in[1];
  const float* cell = (const float*)d_in[2];
  const float* w = (const float*)d_in[3];
  const float* Wqkv = (const float*)d_in[4];
  const float* Wvg = (const float*)d_in[5];
  const float* bvg = (const float*)d_in[6];
  const float* Whg = (const float*)d_in[7];
  const float* bhg = (const float*)d_in[8];
  const float* Wmg = (const float*)d_in[9];
  const float* bmg = (const float*)d_in[10];
  const int* nvec = (const int*)d_in[11];
  float* out = (float*)d_out;
  char* ws = (char*)d_ws;

  short* QA = (short*)(ws + OFF_QA);
  short* KA = (short*)(ws + OFF_KA);
  short* VT = (short*)(ws + OFF_VT);
  short* CT = (short*)(ws + OFF_CT);
  short* ST = (short*)(ws + OFF_ST);
  short* E = (short*)(ws + OFF_E);
  float* GF = (float*)(ws + OFF_GF);

  k_prep<<<96, 512, 0, stream>>>(node_feat, Wqkv, Wvg, bvg, Whg, bhg, Wmg, bmg,
                                 cell, positions, nvec, w, QA, KA, VT, CT, ST,
                                 GF, out + (size_t)NTOT_ * H_);
  k_E<<<dim3(4, 4, 8), 256, 0, stream>>>(QA, KA, CT, ST, E);
  k_out<<<dim3(4, 2, 8), 128, 0, stream>>>(E, VT, GF, out);
}